// Round 1
// baseline (229.315 us; speedup 1.0000x reference)
//
#include <hip/hip_runtime.h>

#define B_  8
#define C_  128
#define H_  96
#define W_  160
#define HWp (H_ * W_)   // 15360 = one channel plane

typedef short  short8  __attribute__((ext_vector_type(8)));
typedef float  floatx4 __attribute__((ext_vector_type(4)));

// round-to-nearest-even fp32 -> bf16, packed pair (a in low 16, b in high 16)
__device__ __forceinline__ unsigned pk_bf16(float a, float b) {
    unsigned ua = __float_as_uint(a);
    unsigned ub = __float_as_uint(b);
    ua = (ua + 0x7FFFu + ((ua >> 16) & 1u)) >> 16;
    ub = (ub + 0x7FFFu + ((ub >> 16) & 1u)) & 0xFFFF0000u;
    return ua | ub;
}

// Band-GEMM correlation:
//   out[b, dy*9+dx, y, x] = (1/128) * sum_c one[b,c,y,x] * two[b,c,y+dy-4,x+dx-4]
// Per (b, y, dy): D[m][n] = sum_k A[m][k]*B[k][n] with A = one row (M=x, K=c),
// B = two row (K=c, N=x2). Band covered by 2 col-tiles at x0-4 and x0+12.
__global__ __launch_bounds__(512, 4)
void corr_kernel(const float* __restrict__ one, const float* __restrict__ two,
                 float* __restrict__ out) {
    // Fragment-order LDS: one record = 16B = one lane's 8 bf16 (k = quad*8+j).
    __shared__ uint4 one_q[8 * 64];     //  8 KB: [y(8)][lane(64)]
    __shared__ uint4 two_q[16 * 128];   // 32 KB: [ry(16)][ct(2)*64 + kg*16 + n]
    unsigned* one_u = reinterpret_cast<unsigned*>(one_q);
    unsigned* two_u = reinterpret_cast<unsigned*>(two_q);

    // grid decode: one batch per XCD (blockIdx&7), y fastest within XCD for L2 halo reuse
    const int id = blockIdx.x;
    const int b  = id & 7;
    const int jj = id >> 3;       // 0..119
    const int yt = jj % 12;
    const int xt = jj / 12;
    const int y0 = yt * 8;
    const int x0 = xt * 16;

    const int tid  = threadIdx.x;
    const int lane = tid & 63;
    const int w    = tid >> 6;    // wave id = y-row within tile

    // staging decomposition for `one`: [x 16][y 8][cphase 4]
    const int o_xl = tid & 15;
    const int o_yl = (tid >> 4) & 7;
    const int o_cp = tid >> 7;                       // 0..3 (k-group)
    // staging decomposition for `two`: [cx 32][ry 16]
    const int t_cx = tid & 31;
    const int t_ry = tid >> 5;                       // 0..15
    const int t_y  = y0 - 4 + t_ry;
    const int t_gx = x0 - 4 + t_cx;
    const bool t_valid = ((unsigned)t_y < H_) && ((unsigned)t_gx < W_) && (t_cx < 24);

    const unsigned o_lbase = (unsigned)(o_yl * 64 + o_cp * 16 + o_xl) * 4u;
    const unsigned t_lbase = (unsigned)(t_ry * 128 + (t_cx >> 4) * 64 + (t_cx & 15)) * 4u;

    floatx4 acc[9][2];
    #pragma unroll
    for (int dy = 0; dy < 9; ++dy) {
        acc[dy][0] = floatx4{0.f, 0.f, 0.f, 0.f};
        acc[dy][1] = floatx4{0.f, 0.f, 0.f, 0.f};
    }

    for (int ck = 0; ck < 4; ++ck) {
        const int c0 = ck * 32;
        if (ck) __syncthreads();

        // ---- stage `one` tile (8y x 16x x 32c) as A fragments ----
        {
            const float* p = one + ((size_t)(b * C_ + c0 + 8 * o_cp) * H_ + (y0 + o_yl)) * W_
                                 + (x0 + o_xl);
            #pragma unroll
            for (int i = 0; i < 4; ++i) {
                float a0 = p[(size_t)(2 * i)     * HWp];
                float a1 = p[(size_t)(2 * i + 1) * HWp];
                one_u[o_lbase + i] = pk_bf16(a0, a1);
            }
        }
        // ---- stage `two` tile (16ry x 32cx x 32c) as B fragments, zero-padded ----
        {
            const float* p = two + ((size_t)(b * C_ + c0) * H_ + t_y) * W_ + t_gx;
            #pragma unroll 4
            for (int it = 0; it < 16; ++it) {
                float a0 = 0.f, a1 = 0.f;
                if (t_valid) {
                    a0 = p[(size_t)(2 * it)     * HWp];
                    a1 = p[(size_t)(2 * it + 1) * HWp];
                }
                two_u[t_lbase + (it >> 2) * 64 + (it & 3)] = pk_bf16(a0, a1);
            }
        }
        __syncthreads();

        // ---- band MFMAs: wave w handles y-row y0+w, all 9 dy x 2 col-tiles ----
        const short8 A = *reinterpret_cast<const short8*>(&one_q[w * 64 + lane]);
        #pragma unroll
        for (int dy = 0; dy < 9; ++dy) {
            const int ry = w + dy;  // staged row index (y + dy - 4 in global coords)
            const short8 Bt0 = *reinterpret_cast<const short8*>(&two_q[ry * 128 + lane]);
            const short8 Bt1 = *reinterpret_cast<const short8*>(&two_q[ry * 128 + 64 + lane]);
            acc[dy][0] = __builtin_amdgcn_mfma_f32_16x16x32_bf16(A, Bt0, acc[dy][0], 0, 0, 0);
            acc[dy][1] = __builtin_amdgcn_mfma_f32_16x16x32_bf16(A, Bt1, acc[dy][1], 0, 0, 0);
        }
    }

    // ---- epilogue: D[m=quad*4+r][n=lane&15]; ct0: dx=n-m, ct1: dx=n-m+16 ----
    const int  qq = lane >> 4;
    const int  nn = lane & 15;
    const int  y  = y0 + w;
    const float scale = 1.0f / (float)C_;
    #pragma unroll
    for (int dy = 0; dy < 9; ++dy) {
        #pragma unroll
        for (int ct = 0; ct < 2; ++ct) {
            floatx4 v = acc[dy][ct];
            #pragma unroll
            for (int r = 0; r < 4; ++r) {
                int m  = qq * 4 + r;
                int dx = nn - m + ct * 16;
                if ((unsigned)dx <= 8u) {
                    size_t o = ((size_t)(b * 81 + dy * 9 + dx) * H_ + y) * W_ + (x0 + m);
                    out[o] = v[r] * scale;
                }
            }
        }
    }
}

extern "C" void kernel_launch(void* const* d_in, const int* in_sizes, int n_in,
                              void* d_out, int out_size, void* d_ws, size_t ws_size,
                              hipStream_t stream) {
    const float* one = (const float*)d_in[0];
    const float* two = (const float*)d_in[1];
    float* out = (float*)d_out;
    // grid: 8 batches * 12 y-tiles * 10 x-tiles = 960 blocks of 512 threads
    corr_kernel<<<dim3(960), dim3(512), 0, stream>>>(one, two, out);
}

// Round 2
// 198.647 us; speedup vs baseline: 1.1544x; 1.1544x over previous
//
#include <hip/hip_runtime.h>

#define B_  8
#define C_  128
#define H_  96
#define W_  160
#define HWp (H_ * W_)   // 15360 = one channel plane

typedef short  short8  __attribute__((ext_vector_type(8)));
typedef float  floatx4 __attribute__((ext_vector_type(4)));

// round-to-nearest-even fp32 -> bf16, packed pair (a low 16, b high 16)
__device__ __forceinline__ unsigned pk_bf16(float a, float b) {
    unsigned ua = __float_as_uint(a);
    unsigned ub = __float_as_uint(b);
    ua = (ua + 0x7FFFu + ((ua >> 16) & 1u)) >> 16;
    ub = (ub + 0x7FFFu + ((ub >> 16) & 1u)) & 0xFFFF0000u;
    return ua | ub;
}

// Band-GEMM correlation, software-pipelined:
//   out[b, dy*9+dx, y, x] = (1/128) * sum_c one[b,c,y,x] * two[b,c,y+dy-4,x+dx-4]
// Chunk loop over C in 4 slices of 32; loads for chunk k+1 issue before chunk k's
// MFMAs (register prefetch), LDS double-buffered -> one barrier per chunk.
__global__ __launch_bounds__(512, 2)
void corr_kernel(const float* __restrict__ one, const float* __restrict__ two,
                 float* __restrict__ out) {
    // Fragment-order LDS records: 16B = one lane's 8 bf16 (k = quad*8 + j).
    __shared__ uint4 one_q[2][8 * 64];     //  8 KB x2: [y(8)][kg(4)*16 + x(16)]
    __shared__ uint4 two_q[2][16 * 128];   // 32 KB x2: [ry(16)][ct(2)*64 + kg(4)*16 + n(16)]

    const int id = blockIdx.x;
    const int b  = id & 7;            // one batch per XCD
    const int jj = id >> 3;           // 0..119
    const int yt = jj % 12;
    const int xt = jj / 12;
    const int y0 = yt * 8;
    const int x0 = xt * 16;

    const int tid  = threadIdx.x;
    const int lane = tid & 63;
    const int w    = tid >> 6;        // wave id = y-row within tile

    // `one` staging: thread -> (x16, y8, kg4); one full 16B record per chunk
    const int o_xl  = tid & 15;
    const int o_yl  = (tid >> 4) & 7;
    const int o_kg  = tid >> 7;                          // 0..3
    const int o_rec = o_yl * 64 + o_kg * 16 + o_xl;

    // `two` staging: thread -> (cx32, ry16); 4 records (all kg) per chunk
    const int t_cx  = tid & 31;
    const int t_ry  = tid >> 5;                          // 0..15
    const int t_y   = y0 - 4 + t_ry;
    const int t_gx  = x0 - 4 + t_cx;
    const bool t_valid = ((unsigned)t_y < H_) && ((unsigned)t_gx < W_) && (t_cx < 24);
    const int t_rec = t_ry * 128 + (t_cx >> 4) * 64 + (t_cx & 15);

    const float* o_base = one + ((size_t)(b * C_ + 8 * o_kg) * H_ + (y0 + o_yl)) * W_ + (x0 + o_xl);
    const float* t_base = two + ((size_t)(b * C_) * H_ + t_y) * W_ + t_gx;

    float ro[8];    // `one` raws: 8 consecutive c at (x,y)
    float rt[32];   // `two` raws: 32 consecutive c at (x2,ry)

    floatx4 acc[9][2];
    #pragma unroll
    for (int dy = 0; dy < 9; ++dy) {
        acc[dy][0] = floatx4{0.f, 0.f, 0.f, 0.f};
        acc[dy][1] = floatx4{0.f, 0.f, 0.f, 0.f};
    }

    // ---- issue loads for chunk 0 ----
    {
        const float* p1 = o_base;
        #pragma unroll
        for (int i = 0; i < 8; ++i) ro[i] = p1[(size_t)i * HWp];
        if (t_valid) {
            const float* p2 = t_base;
            #pragma unroll
            for (int i = 0; i < 32; ++i) rt[i] = p2[(size_t)i * HWp];
        } else {
            #pragma unroll
            for (int i = 0; i < 32; ++i) rt[i] = 0.f;
        }
    }

    #pragma unroll
    for (int ck = 0; ck < 4; ++ck) {
        const int bf = ck & 1;

        // ---- commit chunk ck raws -> LDS (b128 writes, conflict-free) ----
        {
            uint4 v;
            v.x = pk_bf16(ro[0], ro[1]);
            v.y = pk_bf16(ro[2], ro[3]);
            v.z = pk_bf16(ro[4], ro[5]);
            v.w = pk_bf16(ro[6], ro[7]);
            one_q[bf][o_rec] = v;
            #pragma unroll
            for (int kg = 0; kg < 4; ++kg) {
                uint4 u;
                u.x = pk_bf16(rt[kg * 8 + 0], rt[kg * 8 + 1]);
                u.y = pk_bf16(rt[kg * 8 + 2], rt[kg * 8 + 3]);
                u.z = pk_bf16(rt[kg * 8 + 4], rt[kg * 8 + 5]);
                u.w = pk_bf16(rt[kg * 8 + 6], rt[kg * 8 + 7]);
                two_q[bf][t_rec + kg * 16] = u;
            }
        }
        __syncthreads();
        // Single barrier per chunk is safe: next commit targets the OTHER buffer,
        // and a wave can't get 2 chunks ahead (it would have to pass this barrier
        // again before waves still reading the old buffer reach it).

        // ---- issue loads for chunk ck+1 (overlap with MFMAs below) ----
        if (ck < 3) {
            const float* p1 = o_base + (size_t)((ck + 1) * 32) * HWp;
            #pragma unroll
            for (int i = 0; i < 8; ++i) ro[i] = p1[(size_t)i * HWp];
            if (t_valid) {
                const float* p2 = t_base + (size_t)((ck + 1) * 32) * HWp;
                #pragma unroll
                for (int i = 0; i < 32; ++i) rt[i] = p2[(size_t)i * HWp];
            }
        }

        // ---- band MFMAs: wave w = y-row y0+w, 9 dy x 2 col-tiles ----
        const short8 A = *reinterpret_cast<const short8*>(&one_q[bf][w * 64 + lane]);
        #pragma unroll
        for (int dy = 0; dy < 9; ++dy) {
            const int ry = w + dy;
            const short8 Bt0 = *reinterpret_cast<const short8*>(&two_q[bf][ry * 128 + lane]);
            const short8 Bt1 = *reinterpret_cast<const short8*>(&two_q[bf][ry * 128 + 64 + lane]);
            acc[dy][0] = __builtin_amdgcn_mfma_f32_16x16x32_bf16(A, Bt0, acc[dy][0], 0, 0, 0);
            acc[dy][1] = __builtin_amdgcn_mfma_f32_16x16x32_bf16(A, Bt1, acc[dy][1], 0, 0, 0);
        }
    }

    // ---- epilogue: D[m=quad*4+r][n=lane&15]; ct0: dx=n-m, ct1: dx=n-m+16 ----
    const int  qq = lane >> 4;
    const int  nn = lane & 15;
    const int  y  = y0 + w;
    const float scale = 1.0f / (float)C_;
    #pragma unroll
    for (int dy = 0; dy < 9; ++dy) {
        #pragma unroll
        for (int ct = 0; ct < 2; ++ct) {
            floatx4 v = acc[dy][ct];
            #pragma unroll
            for (int r = 0; r < 4; ++r) {
                int m  = qq * 4 + r;
                int dx = nn - m + ct * 16;
                if ((unsigned)dx <= 8u) {
                    size_t o = ((size_t)(b * 81 + dy * 9 + dx) * H_ + y) * W_ + (x0 + m);
                    out[o] = v[r] * scale;
                }
            }
        }
    }
}

extern "C" void kernel_launch(void* const* d_in, const int* in_sizes, int n_in,
                              void* d_out, int out_size, void* d_ws, size_t ws_size,
                              hipStream_t stream) {
    const float* one = (const float*)d_in[0];
    const float* two = (const float*)d_in[1];
    float* out = (float*)d_out;
    // grid: 8 batches * 12 y-tiles * 10 x-tiles = 960 blocks of 512 threads
    corr_kernel<<<dim3(960), dim3(512), 0, stream>>>(one, two, out);
}